// Round 5
// baseline (425.518 us; speedup 1.0000x reference)
//
#include <hip/hip_runtime.h>

// LocalizeAttention3D: out[b,h,(y,x,z), f=(fi,fj,fk), :] = x[b,h,(y+fi-1, x+fj-1, z+fk-1), :]
// with zero padding outside the 24^3 grid. Pure gather, memory-bound.

#define GH 24
#define GW 24
#define GD 24
#define NPOS (GH * GW * GD)   // 13824
#define NBH 16                // b*h = 2*8
#define NDIM 16               // d (feature dim)
#define NF 27                 // 3*3*3 neighborhood

// total output float4 count: NBH * NPOS * NF * (NDIM/4) = 23,887,872  (fits in uint32)

__global__ __launch_bounds__(256) void localize3d_kernel(
    const float4* __restrict__ in,   // [NBH, NPOS, NDIM/4]
    float4* __restrict__ out,        // [NBH, NPOS, NF, NDIM/4]
    unsigned int total4)
{
    unsigned int stride = gridDim.x * blockDim.x;
    for (unsigned int o = blockIdx.x * blockDim.x + threadIdx.x; o < total4; o += stride) {
        // o = (((bh*NPOS + pos)*NF + f) * 4 + dd4)
        unsigned int dd4 = o & 3u;
        unsigned int r   = o >> 2;          // (bh*NPOS + pos)*NF + f
        unsigned int f   = r % NF;
        unsigned int r2  = r / NF;          // bh*NPOS + pos
        unsigned int pos = r2 % NPOS;
        unsigned int bh  = r2 / NPOS;

        unsigned int z  = pos % GD;
        unsigned int xy = pos / GD;
        unsigned int x  = xy % GW;
        unsigned int y  = xy / GW;

        unsigned int fi = f / 9u;
        unsigned int fj = (f / 3u) % 3u;
        unsigned int fk = f % 3u;

        int ny = (int)y + (int)fi - 1;
        int nx = (int)x + (int)fj - 1;
        int nz = (int)z + (int)fk - 1;

        float4 v = make_float4(0.f, 0.f, 0.f, 0.f);
        if ((unsigned)ny < GH && (unsigned)nx < GW && (unsigned)nz < GD) {
            unsigned int npos = ((unsigned)ny * GW + (unsigned)nx) * GD + (unsigned)nz;
            v = in[(bh * NPOS + npos) * 4u + dd4];
        }
        out[o] = v;
    }
}

extern "C" void kernel_launch(void* const* d_in, const int* in_sizes, int n_in,
                              void* d_out, int out_size, void* d_ws, size_t ws_size,
                              hipStream_t stream) {
    const float4* in = (const float4*)d_in[0];
    float4* out = (float4*)d_out;

    unsigned int total4 = (unsigned int)(out_size / 4);   // 23,887,872
    const int block = 256;
    unsigned int nblocks = (total4 + block - 1) / block;
    if (nblocks > 2048u) nblocks = 2048u;   // grid-stride, G11

    localize3d_kernel<<<nblocks, block, 0, stream>>>(in, out, total4);
}

// Round 6
// 405.188 us; speedup vs baseline: 1.0502x; 1.0502x over previous
//
#include <hip/hip_runtime.h>

// LocalizeAttention3D: out[b,h,(y,x,z), f=(fi,fj,fk), :] = x[b,h,(y+fi-1, x+fj-1, z+fk-1), :]
// with zero padding outside the 24^3 grid. Pure gather, memory-bound (write-dominated 27:1).
//
// Round 6 structure: 4 independent float4 outputs per thread, straight-line body.
// Wave owns 256 contiguous output float4s; lane l handles base + j*64 + l (j=0..3),
// so every one of the 4 wave-stores is a contiguous 1KB segment (perfect coalescing),
// and 4 independent loads are in flight before any waitcnt (4x MLP vs round-5 loop).

#define GH 24
#define GW 24
#define GD 24
#define NPOS (GH * GW * GD)   // 13824
#define NF 27

__global__ __launch_bounds__(256) void localize3d_ilp4(
    const float4* __restrict__ in,   // [bh, NPOS, 4]   (4 float4 per voxel, d=16 floats)
    float4* __restrict__ out,        // [bh, NPOS, NF, 4]
    unsigned int total4)
{
    unsigned int t    = blockIdx.x * 256u + threadIdx.x;
    unsigned int lane = t & 63u;
    unsigned int base = (t >> 6) * 256u;      // wave's first output float4

    unsigned int oo[4];
    unsigned int aa[4];
    bool         ok[4];

#pragma unroll
    for (int j = 0; j < 4; ++j) {
        unsigned int o = base + (unsigned)j * 64u + lane;
        oo[j] = o;
        unsigned int dd4 = o & 3u;
        unsigned int r   = o >> 2;            // (bh*NPOS + pos)*27 + f
        unsigned int f   = r % 27u;
        unsigned int q   = r / 27u;           // bh*NPOS + pos
        unsigned int z   = q % 24u;
        unsigned int x   = (q / 24u) % 24u;
        unsigned int y   = (q / 576u) % 24u;  // NPOS = 24*576, so this is y (bh falls out)

        unsigned int fi = f / 9u;
        unsigned int fj = (f / 3u) % 3u;
        unsigned int fk = f % 3u;

        unsigned int uy = y + fi - 1u;        // unsigned wrap: OOB -> >= 24
        unsigned int ux = x + fj - 1u;
        unsigned int uz = z + fk - 1u;
        bool v_ok = (uy < 24u) & (ux < 24u) & (uz < 24u);

        int doff = (int)(fi * 576u + fj * 24u + fk) - 601;   // (fi-1)*576+(fj-1)*24+(fk-1)
        unsigned int a = (unsigned int)((int)q + doff) * 4u + dd4;
        aa[j] = v_ok ? a : 0u;                // branchless: clamp to safe addr
        ok[j] = v_ok && (o < total4);
    }

    float4 v[4];
#pragma unroll
    for (int j = 0; j < 4; ++j) v[j] = in[aa[j]];   // 4 loads in flight, no divergence

#pragma unroll
    for (int j = 0; j < 4; ++j) {
        if (!ok[j]) v[j] = make_float4(0.f, 0.f, 0.f, 0.f);
        if (oo[j] < total4) out[oo[j]] = v[j];
    }
}

extern "C" void kernel_launch(void* const* d_in, const int* in_sizes, int n_in,
                              void* d_out, int out_size, void* d_ws, size_t ws_size,
                              hipStream_t stream) {
    const float4* in = (const float4*)d_in[0];
    float4* out = (float4*)d_out;

    unsigned int total4  = (unsigned int)(out_size / 4);   // 23,887,872
    unsigned int nblocks = (total4 + 1023u) / 1024u;       // 4 float4 per thread, 256 thr
    localize3d_ilp4<<<nblocks, 256, 0, stream>>>(in, out, total4);
}

// Round 8
// 397.424 us; speedup vs baseline: 1.0707x; 1.0195x over previous
//
#include <hip/hip_runtime.h>

// LocalizeAttention3D: out[bh,(y,x,z), f=(fi,fj,fk), :] = x[bh,(y+fi-1,x+fj-1,z+fk-1), :]
// zero-padded outside the 24^3 grid. d=16 floats = 4 float4 per voxel.
//
// Round 7: LDS-staged slab with zero-filled halo.
//  - block = (bh, y, x0..x0+3): 96 consecutive voxels; output = 10368 contiguous float4s
//  - slab = 3(y) x 6(x) x 26(z incl. halo) voxels in LDS (29.9 KB), OOB entries zeroed
//  - inner loop: ds_read_b128 -> global_store_dwordx4, no bounds checks, no divides

#define NF 27

typedef float4 f4;

__global__ __launch_bounds__(256) void localize3d_lds(
    const f4* __restrict__ in,   // [bh, 13824, 4]
    f4* __restrict__ out)        // [bh, 13824, 27, 4]
{
    __shared__ f4 slab[1872];    // (3*6*26) voxels * 4 float4 = 29,952 B

    unsigned bid = blockIdx.x;          // 0..2303
    unsigned xt = bid % 6u;
    unsigned y  = (bid / 6u) % 24u;
    unsigned bh = bid / 144u;
    unsigned x0 = xt * 4u;

    // ---- stage slab (zero halo) ----
    for (unsigned s = threadIdx.x; s < 1872u; s += 256u) {
        unsigned dd4 = s & 3u;
        unsigned sv  = s >> 2;              // 0..467
        unsigned sz  = sv % 26u;
        unsigned sx  = (sv / 26u) % 6u;
        unsigned sy  = sv / 156u;
        int gy = (int)y  + (int)sy - 1;
        int gx = (int)x0 + (int)sx - 1;
        int gz = (int)sz - 1;
        f4 v = make_float4(0.f, 0.f, 0.f, 0.f);
        if ((unsigned)gy < 24u && (unsigned)gx < 24u && (unsigned)gz < 24u) {
            unsigned q = ((bh * 24u + (unsigned)gy) * 24u + (unsigned)gx) * 24u + (unsigned)gz;
            v = in[q * 4u + dd4];
        }
        slab[s] = v;
    }
    __syncthreads();

    // ---- write 10368 contiguous float4s: o' = t + k*256, k = 0..40 (last: t<128) ----
    unsigned t   = threadIdx.x;
    unsigned dd4 = t & 3u;
    unsigned r0  = t >> 2;                 // 0..63
    unsigned lv  = r0 / 27u;               // 0..2
    unsigned f   = r0 - lv * 27u;
    unsigned lx  = 0u;
    unsigned lz  = lv;                     // lv < 24 here

    unsigned q0 = ((bh * 24u + y) * 24u + x0) * 24u;   // block's first voxel
    unsigned ob = q0 * 108u + t;           // output float4 index

#define BODY() do {                                                     \
        unsigned fi = (f * 57u) >> 9;      /* f/9  for f<27 */          \
        unsigned f3 = (f * 171u) >> 9;     /* f/3  for f<27 */          \
        unsigned fj = f3 - fi * 3u;                                     \
        unsigned fk = f - f3 * 3u;                                      \
        unsigned sv = (fi * 6u + lx + fj) * 26u + (lz + fk);            \
        out[ob] = slab[sv * 4u + dd4];                                  \
        ob += 256u;                                                     \
        f += 10u;                          /* r' += 64 = 2*27 + 10 */   \
        unsigned inc = 2u;                                              \
        if (f >= 27u) { f -= 27u; inc = 3u; }                           \
        lz += inc;                                                      \
        if (lz >= 24u) { lz -= 24u; lx += 1u; }                         \
    } while (0)

#pragma unroll 4
    for (int k = 0; k < 40; ++k) { BODY(); }
    if (t < 128u) { BODY(); }              // 10368 = 40*256 + 128
#undef BODY
}

extern "C" void kernel_launch(void* const* d_in, const int* in_sizes, int n_in,
                              void* d_out, int out_size, void* d_ws, size_t ws_size,
                              hipStream_t stream) {
    const f4* in = (const f4*)d_in[0];
    f4* out = (f4*)d_out;
    // grid: 16 bh * 24 y * 6 x-tiles = 2304 blocks, each owns 96 voxels
    localize3d_lds<<<2304, 256, 0, stream>>>(in, out);
}